// Round 1
// 266.288 us; speedup vs baseline: 1.0218x; 1.0218x over previous
//
#include <hip/hip_runtime.h>

typedef _Float16 half8  __attribute__((ext_vector_type(8)));
typedef float    floatx4 __attribute__((ext_vector_type(4)));

#define LOG2E 1.44269504088896340736f

#define NQ  2048
#define NK  2048
#define DIM 512
#define KT  32
#define NTILES 64                 // NK / KT
#define KR_BYTES 32768            // sKr image: 32 rows x 512 f16
#define KT_BYTES 36864            // sKt image: 256 slots x 72 f16
#define IMG_BYTES (KR_BYTES + KT_BYTES)   // 69632 = 68 x 1024-byte chunks
#define WS_NEED ((size_t)8 * NTILES * IMG_BYTES)

// ---------------------------------------------------------------------------
// Layouts (identical to the verified kernel):
// sKr: 32 k-rows x 512d f16, row stride 512. 16B d-groups XOR-swizzled:
//      g' = g ^ key(k), key(k) = ((k&3)<<1)|((k>>2)&1). Conflict-free b128 R/W.
// sKt: K^T pair-slot layout. dp = d>>1, slot = ((dp&3)<<6)|(dp>>2), 72 f16/slot,
//      within-slot offset ((w ^ (dp&3))<<4) + ((d&1)<<3). Stride 144B (odd x16B)
//      -> conflict-free b128 R/W.
// This round: the fp32->fp16 convert + transpose + swizzle is hoisted into a
// one-time prep kernel that writes the EXACT LDS byte image per (batch,ktile)
// into the workspace. The main kernel stages each tile with a pure linear
// global_load_lds DMA copy (no VALU, no VGPR bounce, no ds_write), processes
// 64 q-rows per block (8 waves), and double-buffers tiles with counted vmcnt
// so prefetch loads stay in flight across raw s_barriers.
// ---------------------------------------------------------------------------

// ============================ prep kernel ==================================
__global__ __launch_bounds__(256, 2)
void prep_k(const float* __restrict__ Kg, char* __restrict__ wsK)
{
    __shared__ __align__(16) _Float16 sKr[KT * 512];
    __shared__ __align__(16) _Float16 sKt[256 * 72];

    const int tid  = threadIdx.x;
    const int lane = tid & 63;
    const int wave = tid >> 6;            // 0..3
    const int tileIdx = blockIdx.x;       // batch*64 + kt
    const int batch = tileIdx >> 6;
    const int kt    = tileIdx & 63;

    // ---- identical staging code to the verified kernel ----
    const float* kp = Kg + ((size_t)batch * NK + kt * KT + wave * 8) * DIM + lane * 8;
    float rv[8][8];
    #pragma unroll
    for (int kk = 0; kk < 8; ++kk) {
        float4 f0 = *(const float4*)(kp + kk * DIM);
        float4 f1 = *(const float4*)(kp + kk * DIM + 4);
        rv[kk][0] = f0.x; rv[kk][1] = f0.y; rv[kk][2] = f0.z; rv[kk][3] = f0.w;
        rv[kk][4] = f1.x; rv[kk][5] = f1.y; rv[kk][6] = f1.z; rv[kk][7] = f1.w;
    }
    #pragma unroll
    for (int kk = 0; kk < 8; ++kk) {      // sKr row-major b128, swizzled
        const int row = wave * 8 + kk;
        const int key = ((row & 3) << 1) | ((row >> 2) & 1);
        uint4 w;
        w.x = __builtin_bit_cast(unsigned, __builtin_amdgcn_cvt_pkrtz(rv[kk][0], rv[kk][1]));
        w.y = __builtin_bit_cast(unsigned, __builtin_amdgcn_cvt_pkrtz(rv[kk][2], rv[kk][3]));
        w.z = __builtin_bit_cast(unsigned, __builtin_amdgcn_cvt_pkrtz(rv[kk][4], rv[kk][5]));
        w.w = __builtin_bit_cast(unsigned, __builtin_amdgcn_cvt_pkrtz(rv[kk][6], rv[kk][7]));
        *(uint4*)&sKr[row * 512 + ((lane ^ key) << 3)] = w;
    }
    #pragma unroll
    for (int dd = 0; dd < 8; ++dd) {      // sKt transposed b128, slot layout
        const int pp = dd >> 1;
        const int b  = dd & 1;
        const int slot = (pp << 6) | lane;
        uint4 w;
        w.x = __builtin_bit_cast(unsigned, __builtin_amdgcn_cvt_pkrtz(rv[0][dd], rv[1][dd]));
        w.y = __builtin_bit_cast(unsigned, __builtin_amdgcn_cvt_pkrtz(rv[2][dd], rv[3][dd]));
        w.z = __builtin_bit_cast(unsigned, __builtin_amdgcn_cvt_pkrtz(rv[4][dd], rv[5][dd]));
        w.w = __builtin_bit_cast(unsigned, __builtin_amdgcn_cvt_pkrtz(rv[6][dd], rv[7][dd]));
        *(uint4*)&sKt[slot * 72 + ((wave ^ pp) << 4) + (b << 3)] = w;
    }
    __syncthreads();

    // ---- linear, coalesced LDS-image -> workspace copy (68 KB / block) ----
    char* dst = wsK + (size_t)tileIdx * IMG_BYTES;
    const char* sA = (const char*)sKr;
    const char* sB = (const char*)sKt;
    #pragma unroll
    for (int i = 0; i < 17; ++i) {        // 17 * 4096 = 69632 bytes
        const int off = i * 4096 + tid * 16;
        uint4 v;
        if (off < KR_BYTES) v = *(const uint4*)(sA + off);
        else                v = *(const uint4*)(sB + (off - KR_BYTES));
        *(uint4*)(dst + off) = v;
    }
}

// ============================ main kernel ==================================
__device__ __forceinline__ void gld16(const char* g, char* l)
{
    __builtin_amdgcn_global_load_lds(
        (const __attribute__((address_space(1))) void*)g,
        (__attribute__((address_space(3))) void*)l, 16, 0, 0);
}

__global__ __launch_bounds__(512, 2)
void attn_fa2(const float* __restrict__ Qg, const char* __restrict__ wsK,
              float* __restrict__ Og)
{
    // double-buffered tile images + partial-S exchange: 2*69632 + 16384 = 155648 B
    __shared__ __align__(16) char  sBuf[2][IMG_BYTES];
    __shared__ __align__(16) float sSx[8 * 2 * 64 * 4];

    const int tid  = threadIdx.x;
    const int lane = tid & 63;
    const int wave = tid >> 6;      // 0..7
    const int quad = lane >> 4;
    const int col  = lane & 15;
    const int wq   = wave & 3;      // q-strip (16 rows each, 4 strips)
    const int wg   = wave >> 2;     // d-half
    const int dbase = wg * 256;

    const int batch = blockIdx.x & 7;     // batch -> XCD: images resident in one L2
    const int qtile = blockIdx.x >> 3;    // 0..31 (64 q-rows per block)
    const int qrow  = qtile * 64 + wq * 16 + col;

    const char* img = wsK + (size_t)(batch * NTILES) * IMG_BYTES;

    // ---- Q fragments (B-layout): Q[q=col][d = dbase + dc*32 + quad*8 + j] ----
    const float* qp = Qg + ((size_t)batch * NQ + qrow) * DIM + dbase + quad * 8;
    half8 qf[8];
    #pragma unroll
    for (int dc = 0; dc < 8; ++dc) {
        float4 f0 = *(const float4*)(qp + dc * 32);
        float4 f1 = *(const float4*)(qp + dc * 32 + 4);
        union { unsigned u[4]; half8 h; } t;
        t.u[0] = __builtin_bit_cast(unsigned, __builtin_amdgcn_cvt_pkrtz(f0.x, f0.y));
        t.u[1] = __builtin_bit_cast(unsigned, __builtin_amdgcn_cvt_pkrtz(f0.z, f0.w));
        t.u[2] = __builtin_bit_cast(unsigned, __builtin_amdgcn_cvt_pkrtz(f1.x, f1.y));
        t.u[3] = __builtin_bit_cast(unsigned, __builtin_amdgcn_cvt_pkrtz(f1.z, f1.w));
        qf[dc] = t.h;
    }

    // DMA one tile image (68 x 1KB chunks) into sBuf[bi].
    // waves 0..3: 9 chunks each (0..35); waves 4..7: 8 chunks each (36..67).
    // LDS dest is wave-uniform base; global src carries the per-lane *16B.
    auto issue = [&](int t, int bi) {
        const char* src = img + (size_t)t * IMG_BYTES;
        char* dstb = &sBuf[bi][0];
        if (wave < 4) {
            #pragma unroll
            for (int i = 0; i < 9; ++i) {
                const int c = wave * 9 + i;
                gld16(src + c * 1024 + lane * 16, dstb + c * 1024);
            }
        } else {
            #pragma unroll
            for (int i = 0; i < 8; ++i) {
                const int c = 36 + (wave - 4) * 8 + i;
                gld16(src + c * 1024 + lane * 16, dstb + c * 1024);
            }
        }
    };

    // O^T accumulator: acc[dt] holds O[q=col][d = dbase + dt*16 + quad*4 + r]
    floatx4 acc[16];
    #pragma unroll
    for (int i = 0; i < 16; ++i) acc[i] = (floatx4){0.f, 0.f, 0.f, 0.f};

    float m_run = -INFINITY;
    float l_run = 0.f;
    const int keyc = ((col & 3) << 1) | ((col >> 2) & 1);

    issue(0, 0);   // prologue prefetch (after Q loads so their waits don't drain it)

    for (int kt = 0; kt < NTILES; ++kt) {
        const int bi = kt & 1;
        issue((kt + 1) & (NTILES - 1), bi ^ 1);   // prefetch next tile, other buffer

        // wait own current-tile chunks (counted: the just-issued next-tile loads
        // stay in flight), then converge: tile kt fully resident after barrier.
        if (wave < 4) { asm volatile("s_waitcnt vmcnt(9)" ::: "memory"); }
        else          { asm volatile("s_waitcnt vmcnt(8)" ::: "memory"); }
        __builtin_amdgcn_s_barrier();
        __builtin_amdgcn_sched_barrier(0);

        const _Float16* sKr = (const _Float16*)&sBuf[bi][0];
        const _Float16* sKt = (const _Float16*)&sBuf[bi][KR_BYTES];

        // ---- partial S^T over this wave's d-half ----
        floatx4 s0 = {0.f, 0.f, 0.f, 0.f}, s1 = {0.f, 0.f, 0.f, 0.f};
        #pragma unroll
        for (int dc = 0; dc < 8; ++dc) {
            const int g = wg * 32 + dc * 4 + quad;
            const int off = ((g ^ keyc) << 3);
            half8 a0 = *(const half8*)&sKr[col * 512 + off];
            half8 a1 = *(const half8*)&sKr[(col + 16) * 512 + off];
            s0 = __builtin_amdgcn_mfma_f32_16x16x32_f16(a0, qf[dc], s0, 0, 0, 0);
            s1 = __builtin_amdgcn_mfma_f32_16x16x32_f16(a1, qf[dc], s1, 0, 0, 0);
        }

        // ---- combine d-half partials with partner wave (wave ^ 4) ----
        *(floatx4*)&sSx[((wave * 2 + 0) * 64 + lane) * 4] = s0;
        *(floatx4*)&sSx[((wave * 2 + 1) * 64 + lane) * 4] = s1;
        asm volatile("s_waitcnt lgkmcnt(0)" ::: "memory");
        __builtin_amdgcn_s_barrier();
        __builtin_amdgcn_sched_barrier(0);
        {
            const int pw = wave ^ 4;
            s0 += *(const floatx4*)&sSx[((pw * 2 + 0) * 64 + lane) * 4];
            s1 += *(const floatx4*)&sSx[((pw * 2 + 1) * 64 + lane) * 4];
        }

        // ---- online softmax (q = col lane-local; reduce across quads) ----
        float mloc = fmaxf(fmaxf(fmaxf(s0[0], s0[1]), fmaxf(s0[2], s0[3])),
                           fmaxf(fmaxf(s1[0], s1[1]), fmaxf(s1[2], s1[3])));
        mloc = fmaxf(mloc, __shfl_xor(mloc, 16));
        mloc = fmaxf(mloc, __shfl_xor(mloc, 32));
        const float m_new = fmaxf(m_run, mloc);
        const float alpha = exp2f((m_run - m_new) * LOG2E);
        const float p0 = exp2f((s0[0] - m_new) * LOG2E);
        const float p1 = exp2f((s0[1] - m_new) * LOG2E);
        const float p2 = exp2f((s0[2] - m_new) * LOG2E);
        const float p3 = exp2f((s0[3] - m_new) * LOG2E);
        const float p4 = exp2f((s1[0] - m_new) * LOG2E);
        const float p5 = exp2f((s1[1] - m_new) * LOG2E);
        const float p6 = exp2f((s1[2] - m_new) * LOG2E);
        const float p7 = exp2f((s1[3] - m_new) * LOG2E);
        float sloc = ((p0 + p1) + (p2 + p3)) + ((p4 + p5) + (p6 + p7));
        sloc += __shfl_xor(sloc, 16);
        sloc += __shfl_xor(sloc, 32);
        l_run = l_run * alpha + sloc;
        m_run = m_new;

        #pragma unroll
        for (int i = 0; i < 16; ++i) acc[i] *= alpha;

        // ---- P fragment: B[k = quad*8 + j][q = col] via cross-quad shuffles ----
        const unsigned pk00 = __builtin_bit_cast(unsigned, __builtin_amdgcn_cvt_pkrtz(p0, p1));
        const unsigned pk01 = __builtin_bit_cast(unsigned, __builtin_amdgcn_cvt_pkrtz(p2, p3));
        const unsigned pk10 = __builtin_bit_cast(unsigned, __builtin_amdgcn_cvt_pkrtz(p4, p5));
        const unsigned pk11 = __builtin_bit_cast(unsigned, __builtin_amdgcn_cvt_pkrtz(p6, p7));
        const int srcA = col + ((quad & 1) << 5);
        const int srcB = srcA + 16;
        const unsigned a00 = (unsigned)__shfl((int)pk00, srcA);
        const unsigned a01 = (unsigned)__shfl((int)pk01, srcA);
        const unsigned a10 = (unsigned)__shfl((int)pk10, srcA);
        const unsigned a11 = (unsigned)__shfl((int)pk11, srcA);
        const unsigned b00 = (unsigned)__shfl((int)pk00, srcB);
        const unsigned b01 = (unsigned)__shfl((int)pk01, srcB);
        const unsigned b10 = (unsigned)__shfl((int)pk10, srcB);
        const unsigned b11 = (unsigned)__shfl((int)pk11, srcB);
        const bool hi2 = (quad >= 2);
        union { unsigned u[4]; half8 h; } pt;
        pt.u[0] = hi2 ? a10 : a00;
        pt.u[1] = hi2 ? a11 : a01;
        pt.u[2] = hi2 ? b10 : b00;
        pt.u[3] = hi2 ? b11 : b01;
        const half8 pf = pt.h;

        // ---- O^T += K^T . P^T over this wave's d-half (slot-layout A reads) ----
        #pragma unroll
        for (int dt = 0; dt < 16; ++dt) {
            const int drow = dbase + dt * 16 + col;
            const int dp = drow >> 1;
            const int off = (((dp & 3) << 6) | (dp >> 2)) * 72
                          + ((quad ^ (dp & 3)) << 4) + ((drow & 1) << 3);
            half8 af = *(const half8*)&sKt[off];
            acc[dt] = __builtin_amdgcn_mfma_f32_16x16x32_f16(af, pf, acc[dt], 0, 0, 0);
        }

        // all waves done reading sBuf[bi]; next iteration's issue() overwrites it
        __builtin_amdgcn_s_barrier();
        __builtin_amdgcn_sched_barrier(0);
    }

    // ---- epilogue: normalize and store this wave's d-half ----
    const float inv = 1.f / l_run;
    float* op = Og + ((size_t)batch * NQ + qrow) * DIM + dbase + quad * 4;
    #pragma unroll
    for (int dt = 0; dt < 16; ++dt) {
        floatx4 v = acc[dt] * inv;
        *(floatx4*)(op + dt * 16) = v;
    }
}

// ==================== legacy fallback (verified, 272 us) ====================
__global__ __launch_bounds__(256, 2)
void attn_fa(const float* __restrict__ Qg, const float* __restrict__ Kg,
             float* __restrict__ Og)
{
    __shared__ __align__(16) _Float16 sKr[KT * 512];
    __shared__ __align__(16) _Float16 sKt[256 * 72];
    __shared__ __align__(16) float    sSx[4 * 2 * 64 * 4];

    const int tid  = threadIdx.x;
    const int lane = tid & 63;
    const int wave = tid >> 6;
    const int quad = lane >> 4;
    const int col  = lane & 15;
    const int wq   = wave & 1;
    const int wg   = wave >> 1;
    const int dbase = wg * 256;

    const int batch = blockIdx.x & 7;
    const int qtile = blockIdx.x >> 3;
    const int qrow  = qtile * 32 + wq * 16 + col;

    const float* qp = Qg + ((size_t)batch * NQ + qrow) * DIM + dbase + quad * 8;
    half8 qf[8];
    #pragma unroll
    for (int dc = 0; dc < 8; ++dc) {
        float4 f0 = *(const float4*)(qp + dc * 32);
        float4 f1 = *(const float4*)(qp + dc * 32 + 4);
        union { unsigned u[4]; half8 h; } t;
        t.u[0] = __builtin_bit_cast(unsigned, __builtin_amdgcn_cvt_pkrtz(f0.x, f0.y));
        t.u[1] = __builtin_bit_cast(unsigned, __builtin_amdgcn_cvt_pkrtz(f0.z, f0.w));
        t.u[2] = __builtin_bit_cast(unsigned, __builtin_amdgcn_cvt_pkrtz(f1.x, f1.y));
        t.u[3] = __builtin_bit_cast(unsigned, __builtin_amdgcn_cvt_pkrtz(f1.z, f1.w));
        qf[dc] = t.h;
    }

    floatx4 acc[16];
    #pragma unroll
    for (int i = 0; i < 16; ++i) acc[i] = (floatx4){0.f, 0.f, 0.f, 0.f};

    float m_run = -INFINITY;
    float l_run = 0.f;
    const int keyc = ((col & 3) << 1) | ((col >> 2) & 1);

    for (int kt = 0; kt < NK / KT; ++kt) {
        __syncthreads();
        {
            const float* kp = Kg + ((size_t)batch * NK + kt * KT + wave * 8) * DIM + lane * 8;
            float rv[8][8];
            #pragma unroll
            for (int kk = 0; kk < 8; ++kk) {
                float4 f0 = *(const float4*)(kp + kk * DIM);
                float4 f1 = *(const float4*)(kp + kk * DIM + 4);
                rv[kk][0] = f0.x; rv[kk][1] = f0.y; rv[kk][2] = f0.z; rv[kk][3] = f0.w;
                rv[kk][4] = f1.x; rv[kk][5] = f1.y; rv[kk][6] = f1.z; rv[kk][7] = f1.w;
            }
            #pragma unroll
            for (int kk = 0; kk < 8; ++kk) {
                const int row = wave * 8 + kk;
                const int key = ((row & 3) << 1) | ((row >> 2) & 1);
                uint4 w;
                w.x = __builtin_bit_cast(unsigned, __builtin_amdgcn_cvt_pkrtz(rv[kk][0], rv[kk][1]));
                w.y = __builtin_bit_cast(unsigned, __builtin_amdgcn_cvt_pkrtz(rv[kk][2], rv[kk][3]));
                w.z = __builtin_bit_cast(unsigned, __builtin_amdgcn_cvt_pkrtz(rv[kk][4], rv[kk][5]));
                w.w = __builtin_bit_cast(unsigned, __builtin_amdgcn_cvt_pkrtz(rv[kk][6], rv[kk][7]));
                *(uint4*)&sKr[row * 512 + ((lane ^ key) << 3)] = w;
            }
            #pragma unroll
            for (int dd = 0; dd < 8; ++dd) {
                const int pp = dd >> 1;
                const int b  = dd & 1;
                const int slot = (pp << 6) | lane;
                uint4 w;
                w.x = __builtin_bit_cast(unsigned, __builtin_amdgcn_cvt_pkrtz(rv[0][dd], rv[1][dd]));
                w.y = __builtin_bit_cast(unsigned, __builtin_amdgcn_cvt_pkrtz(rv[2][dd], rv[3][dd]));
                w.z = __builtin_bit_cast(unsigned, __builtin_amdgcn_cvt_pkrtz(rv[4][dd], rv[5][dd]));
                w.w = __builtin_bit_cast(unsigned, __builtin_amdgcn_cvt_pkrtz(rv[6][dd], rv[7][dd]));
                *(uint4*)&sKt[slot * 72 + ((wave ^ pp) << 4) + (b << 3)] = w;
            }
        }
        __syncthreads();

        floatx4 s0 = {0.f, 0.f, 0.f, 0.f}, s1 = {0.f, 0.f, 0.f, 0.f};
        #pragma unroll
        for (int dc = 0; dc < 8; ++dc) {
            const int g = wg * 32 + dc * 4 + quad;
            const int off = ((g ^ keyc) << 3);
            half8 a0 = *(const half8*)&sKr[col * 512 + off];
            half8 a1 = *(const half8*)&sKr[(col + 16) * 512 + off];
            s0 = __builtin_amdgcn_mfma_f32_16x16x32_f16(a0, qf[dc], s0, 0, 0, 0);
            s1 = __builtin_amdgcn_mfma_f32_16x16x32_f16(a1, qf[dc], s1, 0, 0, 0);
        }

        *(floatx4*)&sSx[((wave * 2 + 0) * 64 + lane) * 4] = s0;
        *(floatx4*)&sSx[((wave * 2 + 1) * 64 + lane) * 4] = s1;
        __syncthreads();
        {
            const int pw = wave ^ 2;
            s0 += *(const floatx4*)&sSx[((pw * 2 + 0) * 64 + lane) * 4];
            s1 += *(const floatx4*)&sSx[((pw * 2 + 1) * 64 + lane) * 4];
        }

        float mloc = fmaxf(fmaxf(fmaxf(s0[0], s0[1]), fmaxf(s0[2], s0[3])),
                           fmaxf(fmaxf(s1[0], s1[1]), fmaxf(s1[2], s1[3])));
        mloc = fmaxf(mloc, __shfl_xor(mloc, 16));
        mloc = fmaxf(mloc, __shfl_xor(mloc, 32));
        const float m_new = fmaxf(m_run, mloc);
        const float alpha = exp2f((m_run - m_new) * LOG2E);
        const float p0 = exp2f((s0[0] - m_new) * LOG2E);
        const float p1 = exp2f((s0[1] - m_new) * LOG2E);
        const float p2 = exp2f((s0[2] - m_new) * LOG2E);
        const float p3 = exp2f((s0[3] - m_new) * LOG2E);
        const float p4 = exp2f((s1[0] - m_new) * LOG2E);
        const float p5 = exp2f((s1[1] - m_new) * LOG2E);
        const float p6 = exp2f((s1[2] - m_new) * LOG2E);
        const float p7 = exp2f((s1[3] - m_new) * LOG2E);
        float sloc = ((p0 + p1) + (p2 + p3)) + ((p4 + p5) + (p6 + p7));
        sloc += __shfl_xor(sloc, 16);
        sloc += __shfl_xor(sloc, 32);
        l_run = l_run * alpha + sloc;
        m_run = m_new;

        #pragma unroll
        for (int i = 0; i < 16; ++i) acc[i] *= alpha;

        const unsigned pk00 = __builtin_bit_cast(unsigned, __builtin_amdgcn_cvt_pkrtz(p0, p1));
        const unsigned pk01 = __builtin_bit_cast(unsigned, __builtin_amdgcn_cvt_pkrtz(p2, p3));
        const unsigned pk10 = __builtin_bit_cast(unsigned, __builtin_amdgcn_cvt_pkrtz(p4, p5));
        const unsigned pk11 = __builtin_bit_cast(unsigned, __builtin_amdgcn_cvt_pkrtz(p6, p7));
        const int srcA = col + ((quad & 1) << 5);
        const int srcB = srcA + 16;
        const unsigned a00 = (unsigned)__shfl((int)pk00, srcA);
        const unsigned a01 = (unsigned)__shfl((int)pk01, srcA);
        const unsigned a10 = (unsigned)__shfl((int)pk10, srcA);
        const unsigned a11 = (unsigned)__shfl((int)pk11, srcA);
        const unsigned b00 = (unsigned)__shfl((int)pk00, srcB);
        const unsigned b01 = (unsigned)__shfl((int)pk01, srcB);
        const unsigned b10 = (unsigned)__shfl((int)pk10, srcB);
        const unsigned b11 = (unsigned)__shfl((int)pk11, srcB);
        const bool hi2 = (quad >= 2);
        union { unsigned u[4]; half8 h; } pt;
        pt.u[0] = hi2 ? a10 : a00;
        pt.u[1] = hi2 ? a11 : a01;
        pt.u[2] = hi2 ? b10 : b00;
        pt.u[3] = hi2 ? b11 : b01;
        const half8 pf = pt.h;

        #pragma unroll
        for (int dt = 0; dt < 16; ++dt) {
            const int drow = dbase + dt * 16 + col;
            const int dp = drow >> 1;
            const int off = (((dp & 3) << 6) | (dp >> 2)) * 72
                          + ((quad ^ (dp & 3)) << 4) + ((drow & 1) << 3);
            half8 af = *(const half8*)&sKt[off];
            acc[dt] = __builtin_amdgcn_mfma_f32_16x16x32_f16(af, pf, acc[dt], 0, 0, 0);
        }
    }

    const float inv = 1.f / l_run;
    float* op = Og + ((size_t)batch * NQ + qrow) * DIM + dbase + quad * 4;
    #pragma unroll
    for (int dt = 0; dt < 16; ++dt) {
        floatx4 v = acc[dt] * inv;
        *(floatx4*)(op + dt * 16) = v;
    }
}

extern "C" void kernel_launch(void* const* d_in, const int* in_sizes, int n_in,
                              void* d_out, int out_size, void* d_ws, size_t ws_size,
                              hipStream_t stream) {
    (void)in_sizes; (void)n_in; (void)out_size;
    const float* Q = (const float*)d_in[0];
    const float* K = (const float*)d_in[1];
    float* O = (float*)d_out;
    if (d_ws != nullptr && ws_size >= WS_NEED) {
        char* wsK = (char*)d_ws;
        hipLaunchKernelGGL(prep_k,   dim3(8 * NTILES), dim3(256), 0, stream, K, wsK);
        hipLaunchKernelGGL(attn_fa2, dim3(256),        dim3(512), 0, stream, Q, wsK, O);
    } else {
        hipLaunchKernelGGL(attn_fa,  dim3(512),        dim3(256), 0, stream, Q, K, O);
    }
}

// Round 3
// 213.678 us; speedup vs baseline: 1.2734x; 1.2462x over previous
//
#include <hip/hip_runtime.h>

typedef _Float16 half8   __attribute__((ext_vector_type(8)));
typedef float    floatx4 __attribute__((ext_vector_type(4)));
typedef float    floatx16 __attribute__((ext_vector_type(16)));
typedef unsigned uintx2  __attribute__((ext_vector_type(2)));

#define LOG2E 1.44269504088896340736f

#define NQ  2048
#define NK  2048
#define DIM 512
#define KT  32
#define NTILES 64
#define IMG_BYTES 32768                     // 32 k x 512 d f16, [16][16]-subtiled
#define WS_NEED ((size_t)8 * NTILES * IMG_BYTES)   // 16 MiB

#define PKRT(a,b) __builtin_bit_cast(unsigned, __builtin_amdgcn_cvt_pkrtz((a),(b)))

// ---------------------------------------------------------------------------
// Image layout: f16 offset(k,d) = ((k>>4)*32 + (d>>4))*256 + (k&15)*16 + (d&15)
// ([kb][db][kr][dr] 16x16 subtiles, row-major inside).
//  - QK^T A-frag (row = k = lane&31, 8 contiguous d): plain ds_read_b128.
//  - PV A-frag (row = d = lane&31, 8 contiguous k): ds_read_b64_tr_b16 pairs;
//    per-lane vaddr = region_base + (lane&15)*8, elem j = region row j
//    (4x16 f16 region = 128B contiguous), second 4 rows via offset:128.
// Cross-half (lane^32) exchange: __shfl_xor(x, 32) — the verified primitive
// from the legacy kernel (R2's permlane trick miscompiled: two "+v" operands
// with identical values can be register-coalesced into a self-swap).
// ---------------------------------------------------------------------------

// ============================ prep kernel ==================================
__global__ __launch_bounds__(256, 2)
void prep_k(const float* __restrict__ Kg, char* __restrict__ wsK)
{
    __shared__ __align__(16) _Float16 sImg[KT * DIM];   // 32 KiB
    const int tid = threadIdx.x;
    const int tileIdx = blockIdx.x;          // batch*64 + kt
    const int batch = tileIdx >> 6;
    const int kt    = tileIdx & 63;

    #pragma unroll
    for (int i = 0; i < 4; ++i) {
        const int idx = i * 256 + tid;       // 0..1023 = k(32) x db(32)
        const int k  = idx >> 5;
        const int db = idx & 31;
        const float* kp = Kg + ((size_t)batch * NK + (size_t)kt * KT + k) * DIM + db * 16;
        float4 f0 = *(const float4*)(kp + 0);
        float4 f1 = *(const float4*)(kp + 4);
        float4 f2 = *(const float4*)(kp + 8);
        float4 f3 = *(const float4*)(kp + 12);
        uint4 w0, w1;
        w0.x = PKRT(f0.x, f0.y); w0.y = PKRT(f0.z, f0.w);
        w0.z = PKRT(f1.x, f1.y); w0.w = PKRT(f1.z, f1.w);
        w1.x = PKRT(f2.x, f2.y); w1.y = PKRT(f2.z, f2.w);
        w1.z = PKRT(f3.x, f3.y); w1.w = PKRT(f3.z, f3.w);
        const int off = ((k >> 4) * 32 + db) * 256 + (k & 15) * 16;   // f16 units
        *(uint4*)&sImg[off + 0] = w0;
        *(uint4*)&sImg[off + 8] = w1;
    }
    __syncthreads();
    char* dst = wsK + (size_t)tileIdx * IMG_BYTES;
    const char* src = (const char*)sImg;
    #pragma unroll
    for (int i = 0; i < 8; ++i) {
        const int off = i * 4096 + tid * 16;
        *(uint4*)(dst + off) = *(const uint4*)(src + off);
    }
}

// ============================ main kernel ==================================
__device__ __forceinline__ void gld16(const char* g, char* l)
{
    __builtin_amdgcn_global_load_lds(
        (const __attribute__((address_space(1))) void*)g,
        (__attribute__((address_space(3))) void*)l, 16, 0, 0);
}

__global__ __launch_bounds__(512, 2)
void attn_fa3(const float* __restrict__ Qg, const char* __restrict__ wsK,
              float* __restrict__ Og)
{
    __shared__ __align__(16) char  sK[2][2][IMG_BYTES];   // [stream][buf] 128 KiB
    __shared__ __align__(16) float sSx[8 * 64 * 8];       // 16 KiB -> 147456 total

    const int tid  = threadIdx.x;
    const int lane = tid & 63;
    const int wave = tid >> 6;          // 0..7
    const int strip  = wave & 1;        // q-strip (32 rows)
    const int dh     = (wave >> 1) & 1; // d-half (256)
    const int stream = wave >> 2;       // k-split stream
    const int ql   = lane & 31;
    const int h    = lane >> 5;

    const int batch = blockIdx.x & 7;   // batch -> XCD: image resident in one L2
    const int qtile = blockIdx.x >> 3;  // 0..31
    const int qrow  = qtile * 64 + strip * 32 + ql;
    const int dbase = dh * 256;

    const char* img = wsK + ((size_t)(batch * NTILES + stream * 32)) * IMG_BYTES;

    // ---- Q fragments (B-layout): lane holds Q[qrow][dbase + dc*16 + h*8 + j] ----
    const float* qp = Qg + ((size_t)batch * NQ + qrow) * DIM + dbase + h * 8;
    half8 qf[16];
    #pragma unroll
    for (int dc = 0; dc < 16; ++dc) {
        float4 f0 = *(const float4*)(qp + dc * 16);
        float4 f1 = *(const float4*)(qp + dc * 16 + 4);
        union { unsigned u[4]; half8 hh; } t;
        t.u[0] = PKRT(f0.x, f0.y); t.u[1] = PKRT(f0.z, f0.w);
        t.u[2] = PKRT(f1.x, f1.y); t.u[3] = PKRT(f1.z, f1.w);
        qf[dc] = t.hh;
    }
    asm volatile("" ::: "memory");   // keep Q loads/waits ahead of the DMA queue

    floatx16 acc[8];
    #pragma unroll
    for (int dt = 0; dt < 8; ++dt) {
        #pragma unroll
        for (int e = 0; e < 16; ++e) acc[dt][e] = 0.f;
    }
    float m_run = -INFINITY;
    float l_run = 0.f;

    // lane-constant LDS offsets (bytes)
    const int laneA = ((lane >> 4) & 1) * 16384 + (lane & 15) * 32 + h * 16;
    const int laneT = ((lane >> 4) & 1) * 512 + h * 256 + (lane & 15) * 8;

    // stage one 32KB image: 4 waves per stream x 8 chunks of 1KB
    auto issue = [&](int t, int bi) {
        const char* src = img + (size_t)t * IMG_BYTES;
        char* dst = &sK[stream][bi][0];
        const int cw = (wave & 3) * 8;
        #pragma unroll
        for (int i = 0; i < 8; ++i) {
            const int c = cw + i;
            gld16(src + c * 1024 + lane * 16, dst + c * 1024);
        }
    };

    issue(0, 0);   // prologue prefetch

    for (int kt = 0; kt < 32; ++kt) {
        const int bi = kt & 1;
        issue((kt + 1) & 31, bi ^ 1);    // prefetch next tile, other buffer

        asm volatile("s_waitcnt vmcnt(8)" ::: "memory");  // own current-tile chunks
        __builtin_amdgcn_s_barrier();
        __builtin_amdgcn_sched_barrier(0);

        const char* buf = &sK[stream][bi][0];

        // ---- QK^T partial over this wave's d-half: S^T[32k][32q] ----
        union SS { floatx16 v; floatx4 q[4]; float f[16]; } s;
        {
            floatx16 sv;
            #pragma unroll
            for (int e = 0; e < 16; ++e) sv[e] = 0.f;
            const char* ap = buf + dh * 8192 + laneA;
            #pragma unroll
            for (int dc = 0; dc < 16; ++dc) {
                half8 a = *(const half8*)(ap + dc * 512);
                sv = __builtin_amdgcn_mfma_f32_32x32x16_f16(a, qf[dc], sv, 0, 0, 0);
            }
            s.v = sv;
        }

        // ---- combine d-half partials with partner wave (wave^2), 2 rounds ----
        float* slot  = &sSx[(wave * 64 + lane) * 8];
        const float* pslot = &sSx[((wave ^ 2) * 64 + lane) * 8];
        *(floatx4*)(slot + 0) = s.q[0];
        *(floatx4*)(slot + 4) = s.q[1];
        asm volatile("s_waitcnt lgkmcnt(0)" ::: "memory");
        __builtin_amdgcn_s_barrier();
        __builtin_amdgcn_sched_barrier(0);
        floatx4 r0 = *(const floatx4*)(pslot + 0);
        floatx4 r1 = *(const floatx4*)(pslot + 4);
        asm volatile("s_waitcnt lgkmcnt(0)" ::: "memory");   // reads done before overwrite
        __builtin_amdgcn_s_barrier();
        __builtin_amdgcn_sched_barrier(0);
        *(floatx4*)(slot + 0) = s.q[2];
        *(floatx4*)(slot + 4) = s.q[3];
        s.q[0] += r0; s.q[1] += r1;
        asm volatile("s_waitcnt lgkmcnt(0)" ::: "memory");
        __builtin_amdgcn_s_barrier();
        __builtin_amdgcn_sched_barrier(0);
        floatx4 r2 = *(const floatx4*)(pslot + 0);
        floatx4 r3 = *(const floatx4*)(pslot + 4);
        s.q[2] += r2; s.q[3] += r3;

        // ---- online softmax: q is lane-local (col=lane&31), k split h/h^1 ----
        float mloc = s.f[0];
        #pragma unroll
        for (int r = 1; r < 16; ++r) mloc = fmaxf(mloc, s.f[r]);
        mloc = fmaxf(mloc, __shfl_xor(mloc, 32));
        const float m_new = fmaxf(m_run, mloc);
        const int grow = __any(mloc > m_run);

        float sl = 0.f;
        unsigned pk[8];
        #pragma unroll
        for (int s8 = 0; s8 < 8; ++s8) {
            const float pa = exp2f((s.f[2 * s8]     - m_new) * LOG2E);
            const float pb = exp2f((s.f[2 * s8 + 1] - m_new) * LOG2E);
            sl += pa + pb;
            pk[s8] = PKRT(pa, pb);
        }
        sl += __shfl_xor(sl, 32);
        if (grow) {
            const float alpha = exp2f((m_run - m_new) * LOG2E);
            l_run = l_run * alpha + sl;
            m_run = m_new;
            #pragma unroll
            for (int dt = 0; dt < 8; ++dt) acc[dt] *= alpha;
        } else {
            l_run += sl;
        }

        // ---- P^T B-fragments (k rows, q cols) via cross-half shuffles ----
        unsigned sw[8];
        #pragma unroll
        for (int s8 = 0; s8 < 8; ++s8)
            sw[s8] = (unsigned)__shfl_xor((int)pk[s8], 32);
        union PB { unsigned u[4]; half8 hh; } b0, b1;
        b0.u[0] = h ? sw[2] : pk[0];  b0.u[1] = h ? sw[3] : pk[1];
        b0.u[2] = h ? pk[2] : sw[0];  b0.u[3] = h ? pk[3] : sw[1];
        b1.u[0] = h ? sw[6] : pk[4];  b1.u[1] = h ? sw[7] : pk[5];
        b1.u[2] = h ? pk[6] : sw[4];  b1.u[3] = h ? pk[7] : sw[5];

        // ---- O^T += K^T . P^T, A-frags via hardware transpose reads ----
        const unsigned bufA =
            (unsigned)(size_t)(__attribute__((address_space(3))) const char*)buf
            + (unsigned)(dh * 8192 + laneT);
        #pragma unroll
        for (int dt = 0; dt < 8; ++dt) {
            uintx2 t0, t1, t2, t3;
            const unsigned a0 = bufA + dt * 1024;        // kb = 0
            const unsigned a1 = a0 + 16384;              // kb = 1
            asm volatile(
                "ds_read_b64_tr_b16 %0, %4\n\t"
                "ds_read_b64_tr_b16 %1, %4 offset:128\n\t"
                "ds_read_b64_tr_b16 %2, %5\n\t"
                "ds_read_b64_tr_b16 %3, %5 offset:128"
                : "=&v"(t0), "=&v"(t1), "=&v"(t2), "=&v"(t3)
                : "v"(a0), "v"(a1));
            asm volatile("s_waitcnt lgkmcnt(0)" ::: "memory");
            __builtin_amdgcn_sched_barrier(0);
            union AF { uintx2 d[2]; half8 hh; } A0, A1;
            A0.d[0] = t0; A0.d[1] = t1;
            A1.d[0] = t2; A1.d[1] = t3;
            acc[dt] = __builtin_amdgcn_mfma_f32_32x32x16_f16(A0.hh, b0.hh, acc[dt], 0, 0, 0);
            acc[dt] = __builtin_amdgcn_mfma_f32_32x32x16_f16(A1.hh, b1.hh, acc[dt], 0, 0, 0);
        }

        __builtin_amdgcn_s_barrier();    // all waves done with sK[.][bi] + sSx
        __builtin_amdgcn_sched_barrier(0);
    }

    // ---- epilogue: merge the two k-streams (partner wave^4), store ----
    {
        sSx[(wave * 64 + lane) * 2 + 0] = m_run;
        sSx[(wave * 64 + lane) * 2 + 1] = l_run;
        __syncthreads();
        const float pm = sSx[((wave ^ 4) * 64 + lane) * 2 + 0];
        const float pl = sSx[((wave ^ 4) * 64 + lane) * 2 + 1];
        const float mt   = fmaxf(m_run, pm);
        const float aown = exp2f((m_run - mt) * LOG2E);
        const float aoth = exp2f((pm   - mt) * LOG2E);
        const float lt   = l_run * aown + pl * aoth;
        const float inv  = 1.f / lt;
        (void)aoth;
        __syncthreads();

        float* op = Og + ((size_t)batch * NQ + qrow) * DIM + dbase;
        #pragma unroll
        for (int dt = 0; dt < 8; ++dt) {
            union SS2 { floatx16 v; floatx4 q[4]; } w;
            w.v = acc[dt] * aown;
            if (stream == 1) {
                float* sp = &sSx[(((wave & 3) * 64) + lane) * 16];
                *(floatx4*)(sp + 0)  = w.q[0];
                *(floatx4*)(sp + 4)  = w.q[1];
                *(floatx4*)(sp + 8)  = w.q[2];
                *(floatx4*)(sp + 12) = w.q[3];
            }
            __syncthreads();
            if (stream == 0) {
                const float* sp = &sSx[((wave * 64) + lane) * 16];
                #pragma unroll
                for (int g = 0; g < 4; ++g) {
                    floatx4 r = *(const floatx4*)(sp + g * 4);
                    floatx4 o = (w.q[g] + r) * inv;
                    *(floatx4*)(op + dt * 32 + g * 8 + 4 * h) = o;
                }
            }
            __syncthreads();
        }
    }
}

// ==================== legacy fallback (verified, 272 us) ====================
__global__ __launch_bounds__(256, 2)
void attn_fa(const float* __restrict__ Qg, const float* __restrict__ Kg,
             float* __restrict__ Og)
{
    __shared__ __align__(16) _Float16 sKr[KT * 512];
    __shared__ __align__(16) _Float16 sKt[256 * 72];
    __shared__ __align__(16) float    sSx[4 * 2 * 64 * 4];

    const int tid  = threadIdx.x;
    const int lane = tid & 63;
    const int wave = tid >> 6;
    const int quad = lane >> 4;
    const int col  = lane & 15;
    const int wq   = wave & 1;
    const int wg   = wave >> 1;
    const int dbase = wg * 256;

    const int batch = blockIdx.x & 7;
    const int qtile = blockIdx.x >> 3;
    const int qrow  = qtile * 32 + wq * 16 + col;

    const float* qp = Qg + ((size_t)batch * NQ + qrow) * DIM + dbase + quad * 8;
    half8 qf[8];
    #pragma unroll
    for (int dc = 0; dc < 8; ++dc) {
        float4 f0 = *(const float4*)(qp + dc * 32);
        float4 f1 = *(const float4*)(qp + dc * 32 + 4);
        union { unsigned u[4]; half8 hh; } t;
        t.u[0] = PKRT(f0.x, f0.y); t.u[1] = PKRT(f0.z, f0.w);
        t.u[2] = PKRT(f1.x, f1.y); t.u[3] = PKRT(f1.z, f1.w);
        qf[dc] = t.hh;
    }

    floatx4 acc[16];
    #pragma unroll
    for (int i = 0; i < 16; ++i) acc[i] = (floatx4){0.f, 0.f, 0.f, 0.f};

    float m_run = -INFINITY;
    float l_run = 0.f;
    const int keyc = ((col & 3) << 1) | ((col >> 2) & 1);

    for (int kt = 0; kt < NK / KT; ++kt) {
        __syncthreads();
        {
            const float* kp = Kg + ((size_t)batch * NK + kt * KT + wave * 8) * DIM + lane * 8;
            float rv[8][8];
            #pragma unroll
            for (int kk = 0; kk < 8; ++kk) {
                float4 f0 = *(const float4*)(kp + kk * DIM);
                float4 f1 = *(const float4*)(kp + kk * DIM + 4);
                rv[kk][0] = f0.x; rv[kk][1] = f0.y; rv[kk][2] = f0.z; rv[kk][3] = f0.w;
                rv[kk][4] = f1.x; rv[kk][5] = f1.y; rv[kk][6] = f1.z; rv[kk][7] = f1.w;
            }
            #pragma unroll
            for (int kk = 0; kk < 8; ++kk) {
                const int row = wave * 8 + kk;
                const int key = ((row & 3) << 1) | ((row >> 2) & 1);
                uint4 w;
                w.x = PKRT(rv[kk][0], rv[kk][1]); w.y = PKRT(rv[kk][2], rv[kk][3]);
                w.z = PKRT(rv[kk][4], rv[kk][5]); w.w = PKRT(rv[kk][6], rv[kk][7]);
                *(uint4*)&sKr[row * 512 + ((lane ^ key) << 3)] = w;
            }
            #pragma unroll
            for (int dd = 0; dd < 8; ++dd) {
                const int pp = dd >> 1;
                const int b  = dd & 1;
                const int slot = (pp << 6) | lane;
                uint4 w;
                w.x = PKRT(rv[0][dd], rv[1][dd]); w.y = PKRT(rv[2][dd], rv[3][dd]);
                w.z = PKRT(rv[4][dd], rv[5][dd]); w.w = PKRT(rv[6][dd], rv[7][dd]);
                *(uint4*)&sKt[slot * 72 + ((wave ^ pp) << 4) + (b << 3)] = w;
            }
        }
        __syncthreads();

        floatx4 s0 = {0.f, 0.f, 0.f, 0.f}, s1 = {0.f, 0.f, 0.f, 0.f};
        #pragma unroll
        for (int dc = 0; dc < 8; ++dc) {
            const int g = wg * 32 + dc * 4 + quad;
            const int off = ((g ^ keyc) << 3);
            half8 a0 = *(const half8*)&sKr[col * 512 + off];
            half8 a1 = *(const half8*)&sKr[(col + 16) * 512 + off];
            s0 = __builtin_amdgcn_mfma_f32_16x16x32_f16(a0, qf[dc], s0, 0, 0, 0);
            s1 = __builtin_amdgcn_mfma_f32_16x16x32_f16(a1, qf[dc], s1, 0, 0, 0);
        }

        *(floatx4*)&sSx[((wave * 2 + 0) * 64 + lane) * 4] = s0;
        *(floatx4*)&sSx[((wave * 2 + 1) * 64 + lane) * 4] = s1;
        __syncthreads();
        {
            const int pw = wave ^ 2;
            s0 += *(const floatx4*)&sSx[((pw * 2 + 0) * 64 + lane) * 4];
            s1 += *(const floatx4*)&sSx[((pw * 2 + 1) * 64 + lane) * 4];
        }

        float mloc = fmaxf(fmaxf(fmaxf(s0[0], s0[1]), fmaxf(s0[2], s0[3])),
                           fmaxf(fmaxf(s1[0], s1[1]), fmaxf(s1[2], s1[3])));
        mloc = fmaxf(mloc, __shfl_xor(mloc, 16));
        mloc = fmaxf(mloc, __shfl_xor(mloc, 32));
        const float m_new = fmaxf(m_run, mloc);
        const float alpha = exp2f((m_run - m_new) * LOG2E);
        const float p0 = exp2f((s0[0] - m_new) * LOG2E);
        const float p1 = exp2f((s0[1] - m_new) * LOG2E);
        const float p2 = exp2f((s0[2] - m_new) * LOG2E);
        const float p3 = exp2f((s0[3] - m_new) * LOG2E);
        const float p4 = exp2f((s1[0] - m_new) * LOG2E);
        const float p5 = exp2f((s1[1] - m_new) * LOG2E);
        const float p6 = exp2f((s1[2] - m_new) * LOG2E);
        const float p7 = exp2f((s1[3] - m_new) * LOG2E);
        float sloc = ((p0 + p1) + (p2 + p3)) + ((p4 + p5) + (p6 + p7));
        sloc += __shfl_xor(sloc, 16);
        sloc += __shfl_xor(sloc, 32);
        l_run = l_run * alpha + sloc;
        m_run = m_new;

        #pragma unroll
        for (int i = 0; i < 16; ++i) acc[i] *= alpha;

        const unsigned pk00 = PKRT(p0, p1);
        const unsigned pk01 = PKRT(p2, p3);
        const unsigned pk10 = PKRT(p4, p5);
        const unsigned pk11 = PKRT(p6, p7);
        const int srcA = col + ((quad & 1) << 5);
        const int srcB = srcA + 16;
        const unsigned a00 = (unsigned)__shfl((int)pk00, srcA);
        const unsigned a01 = (unsigned)__shfl((int)pk01, srcA);
        const unsigned a10 = (unsigned)__shfl((int)pk10, srcA);
        const unsigned a11 = (unsigned)__shfl((int)pk11, srcA);
        const unsigned b00 = (unsigned)__shfl((int)pk00, srcB);
        const unsigned b01 = (unsigned)__shfl((int)pk01, srcB);
        const unsigned b10 = (unsigned)__shfl((int)pk10, srcB);
        const unsigned b11 = (unsigned)__shfl((int)pk11, srcB);
        const bool hi2 = (quad >= 2);
        union { unsigned u[4]; half8 hh; } pt;
        pt.u[0] = hi2 ? a10 : a00;
        pt.u[1] = hi2 ? a11 : a01;
        pt.u[2] = hi2 ? b10 : b00;
        pt.u[3] = hi2 ? b11 : b01;
        const half8 pf = pt.hh;

        #pragma unroll
        for (int dt = 0; dt < 16; ++dt) {
            const int drow = dbase + dt * 16 + col;
            const int dp = drow >> 1;
            const int off = (((dp & 3) << 6) | (dp >> 2)) * 72
                          + ((quad ^ (dp & 3)) << 4) + ((drow & 1) << 3);
            half8 af = *(const half8*)&sKt[off];
            acc[dt] = __builtin_amdgcn_mfma_f32_16x16x32_f16(af, pf, acc[dt], 0, 0, 0);
        }
    }

    const float inv = 1.f / l_run;
    float* op = Og + ((size_t)batch * NQ + qrow) * DIM + dbase + quad * 4;
    #pragma unroll
    for (int dt = 0; dt < 16; ++dt) {
        floatx4 v = acc[dt] * inv;
        *(floatx4*)(op + dt * 16) = v;
    }
}

extern "C" void kernel_launch(void* const* d_in, const int* in_sizes, int n_in,
                              void* d_out, int out_size, void* d_ws, size_t ws_size,
                              hipStream_t stream) {
    (void)in_sizes; (void)n_in; (void)out_size;
    const float* Q = (const float*)d_in[0];
    const float* K = (const float*)d_in[1];
    float* O = (float*)d_out;
    if (d_ws != nullptr && ws_size >= WS_NEED) {
        char* wsK = (char*)d_ws;
        hipLaunchKernelGGL(prep_k,   dim3(8 * NTILES), dim3(256), 0, stream, K, wsK);
        hipLaunchKernelGGL(attn_fa3, dim3(256),        dim3(512), 0, stream, Q, wsK, O);
    } else {
        hipLaunchKernelGGL(attn_fa,  dim3(512),        dim3(256), 0, stream, Q, K, O);
    }
}

// Round 4
// 205.901 us; speedup vs baseline: 1.3215x; 1.0378x over previous
//
#include <hip/hip_runtime.h>

typedef _Float16 half8   __attribute__((ext_vector_type(8)));
typedef float    floatx4 __attribute__((ext_vector_type(4)));
typedef float    floatx16 __attribute__((ext_vector_type(16)));
typedef unsigned uintx2  __attribute__((ext_vector_type(2)));

#define LOG2E 1.44269504088896340736f

#define NQ  2048
#define NK  2048
#define DIM 512
#define KT  32
#define NTILES 64
#define IMG_BYTES 32768                     // 32 k x 512 d f16, [16][16]-subtiled
#define WS_NEED ((size_t)8 * NTILES * IMG_BYTES)   // 16 MiB

#define PKRT(a,b) __builtin_bit_cast(unsigned, __builtin_amdgcn_cvt_pkrtz((a),(b)))

// ---------------------------------------------------------------------------
// Image layout: f16 offset(k,d) = ((k>>4)*32 + (d>>4))*256 + (k&15)*16 + (d&15)
// ([kb][db][kr][dr] 16x16 subtiles, row-major inside). Byte:
//   (kb*32+db)*512 + kr*32 + dr*2.
//  - QK^T A-frag (row = k = lane&31, 8 contiguous d): plain ds_read_b128.
//  - PV A-frag (row = d = lane&31, 8 contiguous k): ds_read_b64_tr_b16 pairs.
// R4 changes vs verified R3:
//  - sSx exchange: 32 KB linear layout (wave*4096 + part*1024 + lane*16),
//    conflict-free floor, single round -> 3 barriers/iter instead of 5.
//  - defer-max (THR=8): skip acc rescale unless tile max grows > 8.
//  - s_setprio(1) around MFMA clusters.
//  - prep kernel: no LDS (old version had a 32-way LDS write conflict);
//    write-coalesced direct global stores.
// ---------------------------------------------------------------------------

// ============================ prep kernel ==================================
__global__ __launch_bounds__(256, 2)
void prep_k(const float* __restrict__ Kg, char* __restrict__ wsK)
{
    const int tid = threadIdx.x;
    const int tileIdx = blockIdx.x;          // batch*64 + kt
    const int batch = tileIdx >> 6;
    const int kt    = tileIdx & 63;

    char* img = wsK + (size_t)tileIdx * IMG_BYTES;
    const float* base = Kg + ((size_t)batch * NK + (size_t)kt * KT) * DIM;

    #pragma unroll
    for (int i = 0; i < 4; ++i) {
        const int idx = i * 256 + tid;       // 0..1023
        const int kr  = idx & 15;            // row inside subtile
        const int sub = idx >> 4;            // kb*32 + db  (0..63)
        const int kb  = sub >> 5;
        const int db  = sub & 31;
        const float* kp = base + (size_t)(kb * 16 + kr) * DIM + db * 16;
        float4 f0 = *(const float4*)(kp + 0);
        float4 f1 = *(const float4*)(kp + 4);
        float4 f2 = *(const float4*)(kp + 8);
        float4 f3 = *(const float4*)(kp + 12);
        uint4 w0, w1;
        w0.x = PKRT(f0.x, f0.y); w0.y = PKRT(f0.z, f0.w);
        w0.z = PKRT(f1.x, f1.y); w0.w = PKRT(f1.z, f1.w);
        w1.x = PKRT(f2.x, f2.y); w1.y = PKRT(f2.z, f2.w);
        w1.z = PKRT(f3.x, f3.y); w1.w = PKRT(f3.z, f3.w);
        // 16 consecutive tid (kr) write 512B contiguous -> coalesced
        char* dst = img + sub * 512 + kr * 32;
        *(uint4*)(dst + 0)  = w0;
        *(uint4*)(dst + 16) = w1;
    }
}

// ============================ main kernel ==================================
__device__ __forceinline__ void gld16(const char* g, char* l)
{
    __builtin_amdgcn_global_load_lds(
        (const __attribute__((address_space(1))) void*)g,
        (__attribute__((address_space(3))) void*)l, 16, 0, 0);
}

__global__ __launch_bounds__(512, 2)
void attn_fa4(const float* __restrict__ Qg, const char* __restrict__ wsK,
              float* __restrict__ Og)
{
    __shared__ __align__(16) char  sK[2][2][IMG_BYTES];   // [stream][buf] 128 KiB
    __shared__ __align__(16) float sSx[8192];             // 32 KiB -> 160 KiB total

    const int tid  = threadIdx.x;
    const int lane = tid & 63;
    const int wave = tid >> 6;          // 0..7
    const int strip  = wave & 1;        // q-strip (32 rows)
    const int dh     = (wave >> 1) & 1; // d-half (256)
    const int stream = wave >> 2;       // k-split stream
    const int ql   = lane & 31;
    const int h    = lane >> 5;

    const int batch = blockIdx.x & 7;   // batch -> XCD: image resident in one L2
    const int qtile = blockIdx.x >> 3;  // 0..31
    const int qrow  = qtile * 64 + strip * 32 + ql;
    const int dbase = dh * 256;

    const char* img = wsK + ((size_t)(batch * NTILES + stream * 32)) * IMG_BYTES;

    // ---- Q fragments (B-layout): lane holds Q[qrow][dbase + dc*16 + h*8 + j] ----
    const float* qp = Qg + ((size_t)batch * NQ + qrow) * DIM + dbase + h * 8;
    half8 qf[16];
    #pragma unroll
    for (int dc = 0; dc < 16; ++dc) {
        float4 f0 = *(const float4*)(qp + dc * 16);
        float4 f1 = *(const float4*)(qp + dc * 16 + 4);
        union { unsigned u[4]; half8 hh; } t;
        t.u[0] = PKRT(f0.x, f0.y); t.u[1] = PKRT(f0.z, f0.w);
        t.u[2] = PKRT(f1.x, f1.y); t.u[3] = PKRT(f1.z, f1.w);
        qf[dc] = t.hh;
    }
    asm volatile("" ::: "memory");   // keep Q loads/waits ahead of the DMA queue

    floatx16 acc[8];
    #pragma unroll
    for (int dt = 0; dt < 8; ++dt) {
        #pragma unroll
        for (int e = 0; e < 16; ++e) acc[dt][e] = 0.f;
    }
    float m_run = -INFINITY;
    float l_run = 0.f;

    // lane-constant LDS offsets (bytes)
    const int laneA = ((lane >> 4) & 1) * 16384 + (lane & 15) * 32 + h * 16;
    const int laneT = ((lane >> 4) & 1) * 512 + h * 256 + (lane & 15) * 8;

    // stage one 32KB image: 4 waves per stream x 8 chunks of 1KB
    auto issue = [&](int t, int bi) {
        const char* src = img + (size_t)t * IMG_BYTES;
        char* dst = &sK[stream][bi][0];
        const int cw = (wave & 3) * 8;
        #pragma unroll
        for (int i = 0; i < 8; ++i) {
            const int c = cw + i;
            gld16(src + c * 1024 + lane * 16, dst + c * 1024);
        }
    };

    issue(0, 0);   // prologue prefetch

    for (int kt = 0; kt < 32; ++kt) {
        const int bi = kt & 1;
        issue((kt + 1) & 31, bi ^ 1);    // prefetch next tile, other buffer

        asm volatile("s_waitcnt vmcnt(8)" ::: "memory");  // own current-tile chunks
        __builtin_amdgcn_s_barrier();
        __builtin_amdgcn_sched_barrier(0);

        const char* buf = &sK[stream][bi][0];

        // ---- QK^T partial over this wave's d-half: S^T[32k][32q] ----
        union SS { floatx16 v; floatx4 q[4]; float f[16]; } s;
        {
            floatx16 sv;
            #pragma unroll
            for (int e = 0; e < 16; ++e) sv[e] = 0.f;
            const char* ap = buf + dh * 8192 + laneA;
            __builtin_amdgcn_s_setprio(1);
            #pragma unroll
            for (int dc = 0; dc < 16; ++dc) {
                half8 a = *(const half8*)(ap + dc * 512);
                sv = __builtin_amdgcn_mfma_f32_32x32x16_f16(a, qf[dc], sv, 0, 0, 0);
            }
            __builtin_amdgcn_s_setprio(0);
            s.v = sv;
        }

        // ---- combine d-half partials with partner wave (wave^2), 1 round ----
        {
            float* wp = sSx + wave * 1024 + lane * 4;   // lane-contiguous 1KB/part
            *(floatx4*)(wp + 0)   = s.q[0];
            *(floatx4*)(wp + 256) = s.q[1];
            *(floatx4*)(wp + 512) = s.q[2];
            *(floatx4*)(wp + 768) = s.q[3];
        }
        asm volatile("s_waitcnt lgkmcnt(0)" ::: "memory");
        __builtin_amdgcn_s_barrier();
        __builtin_amdgcn_sched_barrier(0);
        {
            const float* rp = sSx + (wave ^ 2) * 1024 + lane * 4;
            s.q[0] += *(const floatx4*)(rp + 0);
            s.q[1] += *(const floatx4*)(rp + 256);
            s.q[2] += *(const floatx4*)(rp + 512);
            s.q[3] += *(const floatx4*)(rp + 768);
        }

        // ---- online softmax with defer-max (q = lane&31 lane-local) ----
        float mloc = s.f[0];
        #pragma unroll
        for (int r = 1; r < 16; ++r) mloc = fmaxf(mloc, s.f[r]);
        mloc = fmaxf(mloc, __shfl_xor(mloc, 32));
        if (!__all(mloc <= m_run + 8.f)) {       // rescale only on real growth
            const float m_new = fmaxf(m_run, mloc);
            const float alpha = exp2f((m_run - m_new) * LOG2E);
            l_run *= alpha;
            #pragma unroll
            for (int dt = 0; dt < 8; ++dt) acc[dt] *= alpha;
            m_run = m_new;
        }

        float sl = 0.f;
        unsigned pk[8];
        #pragma unroll
        for (int s8 = 0; s8 < 8; ++s8) {
            const float pa = exp2f((s.f[2 * s8]     - m_run) * LOG2E);
            const float pb = exp2f((s.f[2 * s8 + 1] - m_run) * LOG2E);
            sl += pa + pb;
            pk[s8] = PKRT(pa, pb);
        }
        sl += __shfl_xor(sl, 32);
        l_run += sl;

        // ---- P^T B-fragments (k rows, q cols) via cross-half shuffles ----
        unsigned sw[8];
        #pragma unroll
        for (int s8 = 0; s8 < 8; ++s8)
            sw[s8] = (unsigned)__shfl_xor((int)pk[s8], 32);
        union PB { unsigned u[4]; half8 hh; } b0, b1;
        b0.u[0] = h ? sw[2] : pk[0];  b0.u[1] = h ? sw[3] : pk[1];
        b0.u[2] = h ? pk[2] : sw[0];  b0.u[3] = h ? pk[3] : sw[1];
        b1.u[0] = h ? sw[6] : pk[4];  b1.u[1] = h ? sw[7] : pk[5];
        b1.u[2] = h ? pk[6] : sw[4];  b1.u[3] = h ? pk[7] : sw[5];

        // ---- O^T += K^T . P^T, A-frags via hardware transpose reads ----
        const unsigned bufA =
            (unsigned)(size_t)(__attribute__((address_space(3))) const char*)buf
            + (unsigned)(dh * 8192 + laneT);
        __builtin_amdgcn_s_setprio(1);
        #pragma unroll
        for (int dt = 0; dt < 8; ++dt) {
            uintx2 t0, t1, t2, t3;
            const unsigned a0 = bufA + dt * 1024;        // kb = 0
            const unsigned a1 = a0 + 16384;              // kb = 1
            asm volatile(
                "ds_read_b64_tr_b16 %0, %4\n\t"
                "ds_read_b64_tr_b16 %1, %4 offset:128\n\t"
                "ds_read_b64_tr_b16 %2, %5\n\t"
                "ds_read_b64_tr_b16 %3, %5 offset:128"
                : "=&v"(t0), "=&v"(t1), "=&v"(t2), "=&v"(t3)
                : "v"(a0), "v"(a1));
            asm volatile("s_waitcnt lgkmcnt(0)" ::: "memory");
            __builtin_amdgcn_sched_barrier(0);
            union AF { uintx2 d[2]; half8 hh; } A0, A1;
            A0.d[0] = t0; A0.d[1] = t1;
            A1.d[0] = t2; A1.d[1] = t3;
            acc[dt] = __builtin_amdgcn_mfma_f32_32x32x16_f16(A0.hh, b0.hh, acc[dt], 0, 0, 0);
            acc[dt] = __builtin_amdgcn_mfma_f32_32x32x16_f16(A1.hh, b1.hh, acc[dt], 0, 0, 0);
        }
        __builtin_amdgcn_s_setprio(0);

        __builtin_amdgcn_s_barrier();    // all waves done with sK[.][bi] + sSx
        __builtin_amdgcn_sched_barrier(0);
    }

    // ---- epilogue: merge the two k-streams (partner wave^4), store ----
    {
        sSx[(wave * 64 + lane) * 2 + 0] = m_run;
        sSx[(wave * 64 + lane) * 2 + 1] = l_run;
        __syncthreads();
        const float pm = sSx[((wave ^ 4) * 64 + lane) * 2 + 0];
        const float pl = sSx[((wave ^ 4) * 64 + lane) * 2 + 1];
        const float mt   = fmaxf(m_run, pm);
        const float aown = exp2f((m_run - mt) * LOG2E);
        const float aoth = exp2f((pm   - mt) * LOG2E);
        const float lt   = l_run * aown + pl * aoth;
        const float inv  = 1.f / lt;
        (void)aoth;
        __syncthreads();

        float* op = Og + ((size_t)batch * NQ + qrow) * DIM + dbase;
        #pragma unroll
        for (int dt = 0; dt < 8; ++dt) {
            union SS2 { floatx16 v; floatx4 q[4]; } w;
            w.v = acc[dt] * aown;
            if (stream == 1) {
                float* sp = &sSx[(((wave & 3) * 64) + lane) * 16];
                *(floatx4*)(sp + 0)  = w.q[0];
                *(floatx4*)(sp + 4)  = w.q[1];
                *(floatx4*)(sp + 8)  = w.q[2];
                *(floatx4*)(sp + 12) = w.q[3];
            }
            __syncthreads();
            if (stream == 0) {
                const float* sp = &sSx[((wave * 64) + lane) * 16];
                #pragma unroll
                for (int g = 0; g < 4; ++g) {
                    floatx4 r = *(const floatx4*)(sp + g * 4);
                    floatx4 o = (w.q[g] + r) * inv;
                    *(floatx4*)(op + dt * 32 + g * 8 + 4 * h) = o;
                }
            }
            __syncthreads();
        }
    }
}

// ==================== legacy fallback (verified, 272 us) ====================
__global__ __launch_bounds__(256, 2)
void attn_fa(const float* __restrict__ Qg, const float* __restrict__ Kg,
             float* __restrict__ Og)
{
    __shared__ __align__(16) _Float16 sKr[KT * 512];
    __shared__ __align__(16) _Float16 sKt[256 * 72];
    __shared__ __align__(16) float    sSx[4 * 2 * 64 * 4];

    const int tid  = threadIdx.x;
    const int lane = tid & 63;
    const int wave = tid >> 6;
    const int quad = lane >> 4;
    const int col  = lane & 15;
    const int wq   = wave & 1;
    const int wg   = wave >> 1;
    const int dbase = wg * 256;

    const int batch = blockIdx.x & 7;
    const int qtile = blockIdx.x >> 3;
    const int qrow  = qtile * 32 + wq * 16 + col;

    const float* qp = Qg + ((size_t)batch * NQ + qrow) * DIM + dbase + quad * 8;
    half8 qf[8];
    #pragma unroll
    for (int dc = 0; dc < 8; ++dc) {
        float4 f0 = *(const float4*)(qp + dc * 32);
        float4 f1 = *(const float4*)(qp + dc * 32 + 4);
        union { unsigned u[4]; half8 hh; } t;
        t.u[0] = PKRT(f0.x, f0.y); t.u[1] = PKRT(f0.z, f0.w);
        t.u[2] = PKRT(f1.x, f1.y); t.u[3] = PKRT(f1.z, f1.w);
        qf[dc] = t.hh;
    }

    floatx4 acc[16];
    #pragma unroll
    for (int i = 0; i < 16; ++i) acc[i] = (floatx4){0.f, 0.f, 0.f, 0.f};

    float m_run = -INFINITY;
    float l_run = 0.f;
    const int keyc = ((col & 3) << 1) | ((col >> 2) & 1);

    for (int kt = 0; kt < NK / KT; ++kt) {
        __syncthreads();
        {
            const float* kp = Kg + ((size_t)batch * NK + kt * KT + wave * 8) * DIM + lane * 8;
            float rv[8][8];
            #pragma unroll
            for (int kk = 0; kk < 8; ++kk) {
                float4 f0 = *(const float4*)(kp + kk * DIM);
                float4 f1 = *(const float4*)(kp + kk * DIM + 4);
                rv[kk][0] = f0.x; rv[kk][1] = f0.y; rv[kk][2] = f0.z; rv[kk][3] = f0.w;
                rv[kk][4] = f1.x; rv[kk][5] = f1.y; rv[kk][6] = f1.z; rv[kk][7] = f1.w;
            }
            #pragma unroll
            for (int kk = 0; kk < 8; ++kk) {
                const int row = wave * 8 + kk;
                const int key = ((row & 3) << 1) | ((row >> 2) & 1);
                uint4 w;
                w.x = PKRT(rv[kk][0], rv[kk][1]); w.y = PKRT(rv[kk][2], rv[kk][3]);
                w.z = PKRT(rv[kk][4], rv[kk][5]); w.w = PKRT(rv[kk][6], rv[kk][7]);
                *(uint4*)&sKr[row * 512 + ((lane ^ key) << 3)] = w;
            }
            #pragma unroll
            for (int dd = 0; dd < 8; ++dd) {
                const int pp = dd >> 1;
                const int b  = dd & 1;
                const int slot = (pp << 6) | lane;
                uint4 w;
                w.x = PKRT(rv[0][dd], rv[1][dd]); w.y = PKRT(rv[2][dd], rv[3][dd]);
                w.z = PKRT(rv[4][dd], rv[5][dd]); w.w = PKRT(rv[6][dd], rv[7][dd]);
                *(uint4*)&sKt[slot * 72 + ((wave ^ pp) << 4) + (b << 3)] = w;
            }
        }
        __syncthreads();

        floatx4 s0 = {0.f, 0.f, 0.f, 0.f}, s1 = {0.f, 0.f, 0.f, 0.f};
        #pragma unroll
        for (int dc = 0; dc < 8; ++dc) {
            const int g = wg * 32 + dc * 4 + quad;
            const int off = ((g ^ keyc) << 3);
            half8 a0 = *(const half8*)&sKr[col * 512 + off];
            half8 a1 = *(const half8*)&sKr[(col + 16) * 512 + off];
            s0 = __builtin_amdgcn_mfma_f32_16x16x32_f16(a0, qf[dc], s0, 0, 0, 0);
            s1 = __builtin_amdgcn_mfma_f32_16x16x32_f16(a1, qf[dc], s1, 0, 0, 0);
        }

        *(floatx4*)&sSx[((wave * 2 + 0) * 64 + lane) * 4] = s0;
        *(floatx4*)&sSx[((wave * 2 + 1) * 64 + lane) * 4] = s1;
        __syncthreads();
        {
            const int pw = wave ^ 2;
            s0 += *(const floatx4*)&sSx[((pw * 2 + 0) * 64 + lane) * 4];
            s1 += *(const floatx4*)&sSx[((pw * 2 + 1) * 64 + lane) * 4];
        }

        float mloc = fmaxf(fmaxf(fmaxf(s0[0], s0[1]), fmaxf(s0[2], s0[3])),
                           fmaxf(fmaxf(s1[0], s1[1]), fmaxf(s1[2], s1[3])));
        mloc = fmaxf(mloc, __shfl_xor(mloc, 16));
        mloc = fmaxf(mloc, __shfl_xor(mloc, 32));
        const float m_new = fmaxf(m_run, mloc);
        const float alpha = exp2f((m_run - m_new) * LOG2E);
        const float p0 = exp2f((s0[0] - m_new) * LOG2E);
        const float p1 = exp2f((s0[1] - m_new) * LOG2E);
        const float p2 = exp2f((s0[2] - m_new) * LOG2E);
        const float p3 = exp2f((s0[3] - m_new) * LOG2E);
        const float p4 = exp2f((s1[0] - m_new) * LOG2E);
        const float p5 = exp2f((s1[1] - m_new) * LOG2E);
        const float p6 = exp2f((s1[2] - m_new) * LOG2E);
        const float p7 = exp2f((s1[3] - m_new) * LOG2E);
        float sloc = ((p0 + p1) + (p2 + p3)) + ((p4 + p5) + (p6 + p7));
        sloc += __shfl_xor(sloc, 16);
        sloc += __shfl_xor(sloc, 32);
        l_run = l_run * alpha + sloc;
        m_run = m_new;

        #pragma unroll
        for (int i = 0; i < 16; ++i) acc[i] *= alpha;

        const unsigned pk00 = PKRT(p0, p1);
        const unsigned pk01 = PKRT(p2, p3);
        const unsigned pk10 = PKRT(p4, p5);
        const unsigned pk11 = PKRT(p6, p7);
        const int srcA = col + ((quad & 1) << 5);
        const int srcB = srcA + 16;
        const unsigned a00 = (unsigned)__shfl((int)pk00, srcA);
        const unsigned a01 = (unsigned)__shfl((int)pk01, srcA);
        const unsigned a10 = (unsigned)__shfl((int)pk10, srcA);
        const unsigned a11 = (unsigned)__shfl((int)pk11, srcA);
        const unsigned b00 = (unsigned)__shfl((int)pk00, srcB);
        const unsigned b01 = (unsigned)__shfl((int)pk01, srcB);
        const unsigned b10 = (unsigned)__shfl((int)pk10, srcB);
        const unsigned b11 = (unsigned)__shfl((int)pk11, srcB);
        const bool hi2 = (quad >= 2);
        union { unsigned u[4]; half8 hh; } pt;
        pt.u[0] = hi2 ? a10 : a00;
        pt.u[1] = hi2 ? a11 : a01;
        pt.u[2] = hi2 ? b10 : b00;
        pt.u[3] = hi2 ? b11 : b01;
        const half8 pf = pt.hh;

        #pragma unroll
        for (int dt = 0; dt < 16; ++dt) {
            const int drow = dbase + dt * 16 + col;
            const int dp = drow >> 1;
            const int off = (((dp & 3) << 6) | (dp >> 2)) * 72
                          + ((quad ^ (dp & 3)) << 4) + ((drow & 1) << 3);
            half8 af = *(const half8*)&sKt[off];
            acc[dt] = __builtin_amdgcn_mfma_f32_16x16x32_f16(af, pf, acc[dt], 0, 0, 0);
        }
    }

    const float inv = 1.f / l_run;
    float* op = Og + ((size_t)batch * NQ + qrow) * DIM + dbase + quad * 4;
    #pragma unroll
    for (int dt = 0; dt < 16; ++dt) {
        floatx4 v = acc[dt] * inv;
        *(floatx4*)(op + dt * 16) = v;
    }
}

extern "C" void kernel_launch(void* const* d_in, const int* in_sizes, int n_in,
                              void* d_out, int out_size, void* d_ws, size_t ws_size,
                              hipStream_t stream) {
    (void)in_sizes; (void)n_in; (void)out_size;
    const float* Q = (const float*)d_in[0];
    const float* K = (const float*)d_in[1];
    float* O = (float*)d_out;
    if (d_ws != nullptr && ws_size >= WS_NEED) {
        char* wsK = (char*)d_ws;
        hipLaunchKernelGGL(prep_k,   dim3(8 * NTILES), dim3(256), 0, stream, K, wsK);
        hipLaunchKernelGGL(attn_fa4, dim3(256),        dim3(512), 0, stream, Q, wsK, O);
    } else {
        hipLaunchKernelGGL(attn_fa,  dim3(512),        dim3(256), 0, stream, Q, K, O);
    }
}